// Round 20
// baseline (133.208 us; speedup 1.0000x reference)
//
#include <hip/hip_runtime.h>
#include <hip/hip_bf16.h>
#include <math.h>

#define NCAP 10
#define DCAP 16
#define DIN  128
#define NPOS 4096
#define NB   64

typedef short short8 __attribute__((ext_vector_type(8)));
typedef float floatx4 __attribute__((ext_vector_type(4)));

__device__ inline float bflo(unsigned v) { return __uint_as_float(v << 16); }
__device__ inline float bfhi(unsigned v) { return __uint_as_float(v & 0xFFFF0000u); }
__device__ inline unsigned short f2bf(float f) {           // round-to-nearest-even
    unsigned u = __float_as_uint(f);
    return (unsigned short)((u + 0x7FFFu + ((u >> 16) & 1u)) >> 16);
}
__device__ inline float bf2f(unsigned short h) { return __uint_as_float(((unsigned)h) << 16); }

// ===========================================================================
// BIG PATH (ws >= 78,970,880 B) — NO u_hat materialization.
//   partial : f32 [64][32][128]   @ 0          (col-sum partials, 1 MB)
//   wbuf    : f32 [64][10][128]   @ 1,048,576  (w = W @ v per (b,n))
//   pws     : f32 [64][32][10][128] @ 1,376,256 (PV partials, 10.5 MB)
//   ub      : bf16 [64][4096][128] @ 11,862,016 (rounded u, 67 MB, L3-resident)
// Every ws element written before read -> no memset, no atomics.
// ===========================================================================

// Pass A (R8-proven pattern): col-sums of u + bf16 copy ub. 128 pos/block.
__global__ __launch_bounds__(256) void caps_sum_cvt(const float* __restrict__ u,
                                                    float* __restrict__ partial,
                                                    ushort4* __restrict__ ub4) {
    const int b = blockIdx.x;
    const int chunk = blockIdx.y;          // 32 chunks of 128 positions
    const int t = threadIdx.x;
    const int v4 = t & 31;
    const int prow = t >> 5;
    const float4* up = (const float4*)u;
    const size_t posbase = (size_t)b * NPOS + chunk * 128;

    float4 acc = make_float4(0.f, 0.f, 0.f, 0.f);
    #pragma unroll 8
    for (int j = 0; j < 16; ++j) {
        const size_t idx = (posbase + prow + j * 8) * 32 + v4;
        float4 x = up[idx];
        ushort4 h;
        h.x = f2bf(x.x); h.y = f2bf(x.y); h.z = f2bf(x.z); h.w = f2bf(x.w);
        ub4[idx] = h;
        acc.x += x.x; acc.y += x.y; acc.z += x.z; acc.w += x.w;
    }
    __shared__ float4 red[8][32];
    red[prow][v4] = acc;
    __syncthreads();
    if (t < 32) {
        float4 s = red[0][t];
        #pragma unroll
        for (int r = 1; r < 8; ++r) {
            s.x += red[r][t].x; s.y += red[r][t].y;
            s.z += red[r][t].z; s.w += red[r][t].w;
        }
        ((float4*)partial)[((size_t)(b * 32 + chunk)) * 32 + t] = s;
    }
}

// Small per-(b,n): fold partials -> s -> squash -> v -> w (or out). R7-proven.
// MODE 0: src = partial [64][32][128] (scale 0.1), dst = wbuf
// MODE 1: src = pws [64][32][10][128],             dst = wbuf
// MODE 2: src = pws,                               dst = out [64][10][16]
template <int MODE>
__global__ __launch_bounds__(128) void caps_small(const float* __restrict__ src,
                                                  const float* __restrict__ W,
                                                  float* __restrict__ dst) {
    const int b = blockIdx.x / NCAP;
    const int n = blockIdx.x % NCAP;
    const int t = threadIdx.x;             // 128 threads == din index
    __shared__ float xv[DIN];
    __shared__ float vv[DCAP];

    float a = 0.f;
    if (MODE == 0) {
        #pragma unroll 8
        for (int c = 0; c < 32; ++c)
            a += src[(size_t)(b * 32 + c) * DIN + t];
    } else {
        #pragma unroll 8
        for (int c = 0; c < 32; ++c)
            a += src[((size_t)(b * 32 + c) * NCAP + n) * DIN + t];
    }
    xv[t] = a;
    __syncthreads();

    if (t < DCAP) {
        float sv = 0.f;
        for (int d = 0; d < DIN; ++d)
            sv = fmaf(xv[d], W[d * 160 + n * DCAP + t], sv);
        if (MODE == 0) sv *= 0.1f;         // softmax of zeros over 10 capsules
        float nq = sv * sv;
        #pragma unroll
        for (int mm = 8; mm >= 1; mm >>= 1) nq += __shfl_xor(nq, mm, 16);
        nq += 1e-7f;
        const float v = sv * sqrtf(nq) / (1.0f + nq);
        if (MODE == 2)
            dst[(size_t)(b * NCAP + n) * DCAP + t] = v;
        else
            vv[t] = v;
    }
    if (MODE != 2) {
        __syncthreads();
        float wd = 0.f;
        #pragma unroll
        for (int dd = 0; dd < DCAP; ++dd)
            wd = fmaf(W[t * 160 + n * DCAP + dd], vv[dd], wd);
        dst[(size_t)(b * NCAP + n) * DIN + t] = wd;
    }
}

// Routing with MFMA logits, no u_hat. Block = 256 thr / 4 waves owns 128 pos
// (2 subtiles of 64). Per subtile:
//   stage : ub tile 64x128 bf16 -> XOR-swizzled LDS (16-B chunk c at c^(r&7))
//   logits: wave w covers pos [16w,16w+16): 4 MFMA, A = w-frags (10x128 bf16,
//           rows 10..15 zero), B = tile rows. C: lane l -> pos=l&15,
//           n=(l>>4)*4+reg (m89-verified layout).
//   softmax: in-lane over 4 regs + shfl_xor(16,32) folds; publish csm[pos][n].
//   p2    : thread t owns dim d=t&127, n=o*2+(t>>7) (5 outputs), 64-pos fma
//           loop from swizzled LDS; accumulates across subtiles in registers.
__global__ __launch_bounds__(256) void route_mx(const unsigned short* __restrict__ ub,
                                                const float* __restrict__ wbuf,
                                                float* __restrict__ pws) {
    const int b = blockIdx.x;
    const int g = blockIdx.y;              // 32 groups of 128 positions
    const int t = threadIdx.x;
    const int l = t & 63;
    const int w = __builtin_amdgcn_readfirstlane(t >> 6);

    __shared__ __align__(16) uint4 tl[64 * 16];   // 16 KB
    __shared__ float csm[64][10];                 // 2.5 KB

    // ---- A-frags: w rows (n = l&15, zero for n>=10), f32 -> bf16 ----
    const int an = l & 15;
    short8 af[4];
    #pragma unroll
    for (int kk = 0; kk < 4; ++kk) {
        short8 a = {0, 0, 0, 0, 0, 0, 0, 0};
        if (an < 10) {
            const float* wb = wbuf + ((size_t)(b * 10 + an)) * 128 +
                              (kk * 4 + (l >> 4)) * 8;
            const float4 x0 = *(const float4*)wb;
            const float4 x1 = *(const float4*)(wb + 4);
            a[0] = (short)f2bf(x0.x); a[1] = (short)f2bf(x0.y);
            a[2] = (short)f2bf(x0.z); a[3] = (short)f2bf(x0.w);
            a[4] = (short)f2bf(x1.x); a[5] = (short)f2bf(x1.y);
            a[6] = (short)f2bf(x1.z); a[7] = (short)f2bf(x1.w);
        }
        af[kk] = a;
    }

    const int d   = t & 127;               // p2 dim (fixed per thread)
    const int dch = d >> 3;                // 16-B chunk of d
    const int dwd = d & 7;                 // short within chunk
    float acc[5] = {0.f, 0.f, 0.f, 0.f, 0.f};

    for (int s = 0; s < 2; ++s) {
        __syncthreads();                   // tile + csm safe to overwrite
        // ---- stage 64 pos x 128 bf16, swizzled, coalesced ----
        const uint4* src4 = (const uint4*)(ub +
            ((size_t)b * NPOS + g * 128 + s * 64) * DIN);
        #pragma unroll
        for (int i = 0; i < 4; ++i) {
            const int q = t + i * 256;     // 1024 chunks
            const int r = q >> 4, c = q & 15;
            tl[r * 16 + (c ^ (r & 7))] = src4[q];
        }
        __syncthreads();

        // ---- logits via MFMA ----
        floatx4 lg = {0.f, 0.f, 0.f, 0.f};
        #pragma unroll
        for (int kk = 0; kk < 4; ++kk) {
            const int br = w * 16 + (l & 15);
            const int q = kk * 4 + (l >> 4);
            const short8 bf = *(const short8*)&tl[br * 16 + (q ^ (br & 7))];
            lg = __builtin_amdgcn_mfma_f32_16x16x32_bf16(af[kk], bf, lg, 0, 0, 0);
        }

        // ---- softmax over n (10 valid rows) ----
        const int ng = (l >> 4) * 4;
        float m = -1e30f;
        #pragma unroll
        for (int r2 = 0; r2 < 4; ++r2)
            if (ng + r2 < 10) m = fmaxf(m, lg[r2]);
        m = fmaxf(m, __shfl_xor(m, 16));
        m = fmaxf(m, __shfl_xor(m, 32));
        float e[4];
        float ss = 0.f;
        #pragma unroll
        for (int r2 = 0; r2 < 4; ++r2) {
            e[r2] = (ng + r2 < 10) ? __expf(lg[r2] - m) : 0.f;
            ss += e[r2];
        }
        ss += __shfl_xor(ss, 16);
        ss += __shfl_xor(ss, 32);
        const float inv = 1.0f / ss;
        const int posl = w * 16 + (l & 15);
        #pragma unroll
        for (int r2 = 0; r2 < 4; ++r2)
            if (ng + r2 < 10) csm[posl][ng + r2] = e[r2] * inv;
        __syncthreads();

        // ---- p2: accumulate c[n]*u over 64 positions ----
        const short* tls = (const short*)tl;
        #pragma unroll
        for (int o = 0; o < 5; ++o) {
            const int n = o * 2 + (t >> 7);
            float a2 = acc[o];
            for (int p = 0; p < 64; ++p) {
                const float uv = bf2f((unsigned short)
                    tls[p * 128 + ((dch ^ (p & 7)) << 3) + dwd]);
                a2 = fmaf(csm[p][n], uv, a2);
            }
            acc[o] = a2;
        }
    }

    #pragma unroll
    for (int o = 0; o < 5; ++o)
        pws[(size_t)(b * 32 + g) * 1280 + o * 256 + t] = acc[o];
}

// ===========================================================================
// FALLBACK PATH (R7, verified): f32 routing against w = W @ v.
// ws: partial f32[64][16][128] @0 ; wbuf @131072 f ; pws32 @212992 f (5.25MB)
// ===========================================================================

__global__ __launch_bounds__(256) void caps_sum(const float* __restrict__ u,
                                                float* __restrict__ partial) {
    const int b = blockIdx.x;
    const int chunk = blockIdx.y;
    const int t = threadIdx.x;
    const int v4 = t & 31;
    const int prow = t >> 5;
    const float4* up = (const float4*)u;
    const size_t posbase = (size_t)b * NPOS + chunk * 256;
    float4 acc = make_float4(0.f, 0.f, 0.f, 0.f);
    #pragma unroll 8
    for (int j = 0; j < 32; ++j) {
        float4 x = up[(posbase + prow + j * 8) * 32 + v4];
        acc.x += x.x; acc.y += x.y; acc.z += x.z; acc.w += x.w;
    }
    __shared__ float4 red[8][32];
    red[prow][v4] = acc;
    __syncthreads();
    if (t < 32) {
        float4 s = red[0][t];
        #pragma unroll
        for (int r = 1; r < 8; ++r) {
            s.x += red[r][t].x; s.y += red[r][t].y;
            s.z += red[r][t].z; s.w += red[r][t].w;
        }
        ((float4*)partial)[((size_t)b * 16 + chunk) * 32 + t] = s;
    }
}

template <int MODE>
__global__ __launch_bounds__(128) void caps_small16(const float* __restrict__ src,
                                                    const float* __restrict__ W,
                                                    float* __restrict__ dst) {
    const int b = blockIdx.x / NCAP;
    const int n = blockIdx.x % NCAP;
    const int t = threadIdx.x;
    __shared__ float xv[DIN];
    __shared__ float vv[DCAP];
    float a = 0.f;
    if (MODE == 0) {
        #pragma unroll 4
        for (int c = 0; c < 16; ++c) a += src[(size_t)(b * 16 + c) * DIN + t];
    } else {
        #pragma unroll 4
        for (int c = 0; c < 16; ++c) a += src[((size_t)(b * 16 + c) * NCAP + n) * DIN + t];
    }
    xv[t] = a;
    __syncthreads();
    if (t < DCAP) {
        float sv = 0.f;
        for (int d = 0; d < DIN; ++d) sv = fmaf(xv[d], W[d * 160 + n * DCAP + t], sv);
        if (MODE == 0) sv *= 0.1f;
        float nq = sv * sv;
        #pragma unroll
        for (int mm = 8; mm >= 1; mm >>= 1) nq += __shfl_xor(nq, mm, 16);
        nq += 1e-7f;
        const float v = sv * sqrtf(nq) / (1.0f + nq);
        if (MODE == 2) dst[(size_t)(b * NCAP + n) * DCAP + t] = v;
        else vv[t] = v;
    }
    if (MODE != 2) {
        __syncthreads();
        float wd = 0.f;
        #pragma unroll
        for (int dd = 0; dd < DCAP; ++dd)
            wd = fmaf(W[t * 160 + n * DCAP + dd], vv[dd], wd);
        dst[(size_t)(b * NCAP + n) * DIN + t] = wd;
    }
}

__global__ __launch_bounds__(256, 3) void caps_route(const float* __restrict__ u,
                                                     const float* __restrict__ wsrc,
                                                     float* __restrict__ pdst) {
    const int b = blockIdx.x;
    const int tile = blockIdx.y;
    const int t = threadIdx.x;
    const int lane = t & 63;
    const int wv = __builtin_amdgcn_readfirstlane(t >> 6);
    __shared__ float4 tl4[64 * 32];
    __shared__ float lgp[4][64][11];
    float* tlf = (float*)tl4;
    const float4* wq4 = (const float4*)(wsrc + (size_t)b * (NCAP * DIN));
    float acc0[NCAP], acc1[NCAP];
    #pragma unroll
    for (int n = 0; n < NCAP; ++n) { acc0[n] = 0.f; acc1[n] = 0.f; }
    for (int s = 0; s < 4; ++s) {
        __syncthreads();
        const float4* src4 = (const float4*)u + ((size_t)b * NPOS + tile * 256 + s * 64) * 32;
        #pragma unroll
        for (int i = 0; i < 8; ++i) {
            const int q = t + i * 256;
            const int r = q >> 5, c = q & 31;
            tl4[r * 32 + (c ^ (r & 7))] = src4[q];
        }
        __syncthreads();
        float lg[NCAP];
        #pragma unroll
        for (int n = 0; n < NCAP; ++n) lg[n] = 0.f;
        #pragma unroll
        for (int j = 0; j < 8; ++j) {
            const float4 u4 = tl4[lane * 32 + wv * 8 + (j ^ (lane & 7))];
            #pragma unroll
            for (int n = 0; n < NCAP; ++n) {
                const float4 w4 = wq4[n * 32 + wv * 8 + j];
                lg[n] = fmaf(u4.x, w4.x, fmaf(u4.y, w4.y,
                        fmaf(u4.z, w4.z, fmaf(u4.w, w4.w, lg[n]))));
            }
        }
        #pragma unroll
        for (int n = 0; n < NCAP; ++n) lgp[wv][lane][n] = lg[n];
        __syncthreads();
        float c[NCAP];
        float m = -1e30f;
        #pragma unroll
        for (int n = 0; n < NCAP; ++n) {
            c[n] = lgp[0][lane][n] + lgp[1][lane][n] + lgp[2][lane][n] + lgp[3][lane][n];
            m = fmaxf(m, c[n]);
        }
        float ssum = 0.f;
        #pragma unroll
        for (int n = 0; n < NCAP; ++n) { c[n] = __expf(c[n] - m); ssum += c[n]; }
        const float inv = 1.0f / ssum;
        #pragma unroll
        for (int n = 0; n < NCAP; ++n) c[n] *= inv;
        const int col0 = lane >> 2, word = lane & 3;
        #pragma unroll
        for (int i = 0; i < 16; ++i) {
            const int p = wv * 16 + i;
            const int ca = col0 ^ (p & 7);
            const float u0 = tlf[(p * 32 + ca) * 4 + word];
            const float u1 = tlf[(p * 32 + ca + 16) * 4 + word];
            #pragma unroll
            for (int n = 0; n < NCAP; ++n) {
                const float cp = __int_as_float(
                    __builtin_amdgcn_readlane(__float_as_int(c[n]), p));
                acc0[n] = fmaf(cp, u0, acc0[n]);
                acc1[n] = fmaf(cp, u1, acc1[n]);
            }
        }
    }
    __syncthreads();
    float* red = tlf;
    #pragma unroll
    for (int n = 0; n < NCAP; ++n) {
        red[(wv * NCAP + n) * DIN + lane]      = acc0[n];
        red[(wv * NCAP + n) * DIN + lane + 64] = acc1[n];
    }
    __syncthreads();
    float* pb = pdst + (size_t)(b * 16 + tile) * (NCAP * DIN);
    for (int k = t; k < NCAP * DIN; k += 256)
        pb[k] = red[k] + red[1280 + k] + red[2560 + k] + red[3840 + k];
}

extern "C" void kernel_launch(void* const* d_in, const int* in_sizes, int n_in,
                              void* d_out, int out_size, void* d_ws, size_t ws_size,
                              hipStream_t stream) {
    const float* u = (const float*)d_in[0];   // [64][4096][128]
    const float* W = (const float*)d_in[1];   // [128][160]
    float* out = (float*)d_out;               // [64][10][16]
    char* wsb = (char*)d_ws;

    if (ws_size >= 78970880ull) {
        float* partial = (float*)wsb;                       // 1 MB
        float* wbuf    = (float*)(wsb + 1048576);           // 320 KB
        float* pws     = (float*)(wsb + 1376256);           // 10.5 MB
        unsigned short* ub = (unsigned short*)(wsb + 11862016); // 67 MB bf16

        caps_sum_cvt<<<dim3(NB, 32), 256, 0, stream>>>(u, partial, (ushort4*)ub);
        caps_small<0><<<NB * NCAP, 128, 0, stream>>>(partial, W, wbuf);   // v1->w1
        route_mx<<<dim3(NB, 32), 256, 0, stream>>>(ub, wbuf, pws);        // iter 2
        caps_small<1><<<NB * NCAP, 128, 0, stream>>>(pws, W, wbuf);       // v2->w2
        route_mx<<<dim3(NB, 32), 256, 0, stream>>>(ub, wbuf, pws);        // iter 3
        caps_small<2><<<NB * NCAP, 128, 0, stream>>>(pws, W, out);        // v3->out
    } else {
        float* partial = (float*)wsb;
        float* wbuf    = (float*)wsb + 131072;
        float* pws32   = (float*)wsb + 212992;
        caps_sum<<<dim3(NB, 16), 256, 0, stream>>>(u, partial);
        caps_small16<0><<<NB * NCAP, 128, 0, stream>>>(partial, W, wbuf);
        caps_route<<<dim3(NB, 16), 256, 0, stream>>>(u, wbuf, pws32);
        caps_small16<1><<<NB * NCAP, 128, 0, stream>>>(pws32, W, wbuf);
        caps_route<<<dim3(NB, 16), 256, 0, stream>>>(u, wbuf, pws32);
        caps_small16<2><<<NB * NCAP, 128, 0, stream>>>(pws32, W, out);
    }
}

// Round 21
// 109.753 us; speedup vs baseline: 1.2137x; 1.2137x over previous
//
#include <hip/hip_runtime.h>
#include <hip/hip_bf16.h>
#include <math.h>

#define NCAP 10
#define DCAP 16
#define DIN  128
#define NPOS 4096
#define NB   64

typedef short short8 __attribute__((ext_vector_type(8)));
typedef float floatx4 __attribute__((ext_vector_type(4)));

__device__ inline float bflo(unsigned v) { return __uint_as_float(v << 16); }
__device__ inline float bfhi(unsigned v) { return __uint_as_float(v & 0xFFFF0000u); }
__device__ inline unsigned short f2bf(float f) {           // round-to-nearest-even
    unsigned u = __float_as_uint(f);
    return (unsigned short)((u + 0x7FFFu + ((u >> 16) & 1u)) >> 16);
}

// ===========================================================================
// ws layout (11.9 MB total — no big materialization):
//   partial : f32 [64][32][128]     @ 0          (col-sum partials, 1 MB)
//   wbuf    : f32 [64][10][128]     @ 1,048,576  (w = W @ v per (b,n))
//   pws     : f32 [64][32][10][128] @ 1,376,256  (PV partials, 10.5 MB)
// All passes over u are PURE READS (u stays L3-resident after pass 1);
// measured: mixed 134R+67W streams run 2.5 TB/s vs 5.4 TB/s pure-read.
// Every ws element written before read -> no memset, no atomics.
// ===========================================================================

// Pass A: per-batch column sums of u (read-only). 128 pos per block.
__global__ __launch_bounds__(256) void caps_sum(const float* __restrict__ u,
                                                float* __restrict__ partial) {
    const int b = blockIdx.x;
    const int chunk = blockIdx.y;          // 32 chunks of 128 positions
    const int t = threadIdx.x;
    const int v4 = t & 31;
    const int prow = t >> 5;
    const float4* up = (const float4*)u;
    const size_t posbase = (size_t)b * NPOS + chunk * 128;

    float4 acc = make_float4(0.f, 0.f, 0.f, 0.f);
    #pragma unroll 8
    for (int j = 0; j < 16; ++j) {
        const size_t idx = (posbase + prow + j * 8) * 32 + v4;
        float4 x = up[idx];
        acc.x += x.x; acc.y += x.y; acc.z += x.z; acc.w += x.w;
    }
    __shared__ float4 red[8][32];
    red[prow][v4] = acc;
    __syncthreads();
    if (t < 32) {
        float4 s = red[0][t];
        #pragma unroll
        for (int r = 1; r < 8; ++r) {
            s.x += red[r][t].x; s.y += red[r][t].y;
            s.z += red[r][t].z; s.w += red[r][t].w;
        }
        ((float4*)partial)[((size_t)(b * 32 + chunk)) * 32 + t] = s;
    }
}

// Small per-(b,n): fold 32 chunk-partials -> s -> squash -> v -> w (or out).
// MODE 0: src = partial (scale 0.1), dst = wbuf
// MODE 1: src = pws,                 dst = wbuf
// MODE 2: src = pws,                 dst = out [64][10][16]
template <int MODE>
__global__ __launch_bounds__(128) void caps_small(const float* __restrict__ src,
                                                  const float* __restrict__ W,
                                                  float* __restrict__ dst) {
    const int b = blockIdx.x / NCAP;
    const int n = blockIdx.x % NCAP;
    const int t = threadIdx.x;             // 128 threads == din index
    __shared__ float xv[DIN];
    __shared__ float vv[DCAP];

    float a = 0.f;
    if (MODE == 0) {
        #pragma unroll 8
        for (int c = 0; c < 32; ++c)
            a += src[(size_t)(b * 32 + c) * DIN + t];
    } else {
        #pragma unroll 8
        for (int c = 0; c < 32; ++c)
            a += src[((size_t)(b * 32 + c) * NCAP + n) * DIN + t];
    }
    xv[t] = a;
    __syncthreads();

    if (t < DCAP) {
        float sv = 0.f;
        for (int d = 0; d < DIN; ++d)
            sv = fmaf(xv[d], W[d * 160 + n * DCAP + t], sv);
        if (MODE == 0) sv *= 0.1f;         // softmax of zeros over 10 capsules
        float nq = sv * sv;
        #pragma unroll
        for (int mm = 8; mm >= 1; mm >>= 1) nq += __shfl_xor(nq, mm, 16);
        nq += 1e-7f;
        const float v = sv * sqrtf(nq) / (1.0f + nq);
        if (MODE == 2)
            dst[(size_t)(b * NCAP + n) * DCAP + t] = v;
        else
            vv[t] = v;
    }
    if (MODE != 2) {
        __syncthreads();
        float wd = 0.f;
        #pragma unroll
        for (int dd = 0; dd < DCAP; ++dd)
            wd = fmaf(W[t * 160 + n * DCAP + dd], vv[dd], wd);
        dst[(size_t)(b * NCAP + n) * DIN + t] = wd;
    }
}

// Routing pass, pure-read over u (L3-resident). Block = 256 thr / 4 waves
// owns 128 pos (2 subtiles of 64). Per subtile:
//   stage : f32 u tile -> bf16 in-register -> XOR-swizzled LDS (16B chunk c
//           stored at c^(r&7)); coalesced reads.
//   logits: wave w covers pos [16w,16w+16): 4 MFMA (A = w-frags from wbuf,
//           rows 10..15 zero; B = tile rows). C: lane l -> pos=l&15,
//           n=(l>>4)*4+reg (R20-verified numerically).
//   softmax: in-lane + shfl_xor(16,32) folds; publish csm[pos][n] (pad 12).
//   p2    : thread owns dim-pair {2*d2, 2*d2+1}, wave w owns pos-quarter
//           [16w,16w+16): all lanes share p -> csm reads are broadcasts;
//           1 b32 u-read + 20 fma per pos. Accumulate acc[10][2] in regs.
//   fold  : 4 pos-quarter partials folded via LDS (reuses tile), one
//           coalesced pws store [10][128] per block.
__global__ __launch_bounds__(256) void route_fx(const float* __restrict__ u,
                                                const float* __restrict__ wbuf,
                                                float* __restrict__ pws) {
    const int b = blockIdx.x;
    const int g = blockIdx.y;              // 32 groups of 128 positions
    const int t = threadIdx.x;
    const int l = t & 63;
    const int w = __builtin_amdgcn_readfirstlane(t >> 6);

    __shared__ __align__(16) char smem[20480 + 64 * 12 * 4];
    uint4* tile = (uint4*)smem;            // [64][16] uint4 (16 KB)
    float (*csm)[12] = (float (*)[12])(smem + 20480);   // [64][12]

    // ---- A-frags: w rows (n = l&15, zero for n>=10), f32 -> bf16 ----
    const int an = l & 15;
    short8 af[4];
    #pragma unroll
    for (int kk = 0; kk < 4; ++kk) {
        short8 a = {0, 0, 0, 0, 0, 0, 0, 0};
        if (an < 10) {
            const float* wb = wbuf + ((size_t)(b * 10 + an)) * 128 +
                              (kk * 4 + (l >> 4)) * 8;
            const float4 x0 = *(const float4*)wb;
            const float4 x1 = *(const float4*)(wb + 4);
            a[0] = (short)f2bf(x0.x); a[1] = (short)f2bf(x0.y);
            a[2] = (short)f2bf(x0.z); a[3] = (short)f2bf(x0.w);
            a[4] = (short)f2bf(x1.x); a[5] = (short)f2bf(x1.y);
            a[6] = (short)f2bf(x1.z); a[7] = (short)f2bf(x1.w);
        }
        af[kk] = a;
    }

    const int d2 = t & 63;                 // dim-pair index (dims 2*d2, 2*d2+1)
    float acc[NCAP][2];
    #pragma unroll
    for (int n = 0; n < NCAP; ++n) { acc[n][0] = 0.f; acc[n][1] = 0.f; }

    for (int s = 0; s < 2; ++s) {
        __syncthreads();                   // tile + csm safe to overwrite
        // ---- stage: f32 reads (coalesced) -> bf16 -> swizzled LDS ----
        const float4* src4 = (const float4*)u +
            ((size_t)b * NPOS + g * 128 + s * 64) * 32;
        #pragma unroll
        for (int i = 0; i < 4; ++i) {
            const int q = t + i * 256;     // 1024 chunks of 8 bf16
            const int r = q >> 4, c = q & 15;
            const float4 x0 = src4[r * 32 + c * 2];
            const float4 x1 = src4[r * 32 + c * 2 + 1];
            uint4 h;
            h.x = (unsigned)f2bf(x0.x) | ((unsigned)f2bf(x0.y) << 16);
            h.y = (unsigned)f2bf(x0.z) | ((unsigned)f2bf(x0.w) << 16);
            h.z = (unsigned)f2bf(x1.x) | ((unsigned)f2bf(x1.y) << 16);
            h.w = (unsigned)f2bf(x1.z) | ((unsigned)f2bf(x1.w) << 16);
            tile[r * 16 + (c ^ (r & 7))] = h;
        }
        __syncthreads();

        // ---- logits via MFMA (R20-verified) ----
        floatx4 lg = {0.f, 0.f, 0.f, 0.f};
        #pragma unroll
        for (int kk = 0; kk < 4; ++kk) {
            const int br = w * 16 + (l & 15);
            const int q = kk * 4 + (l >> 4);
            const short8 bf = *(const short8*)&tile[br * 16 + (q ^ (br & 7))];
            lg = __builtin_amdgcn_mfma_f32_16x16x32_bf16(af[kk], bf, lg, 0, 0, 0);
        }

        // ---- softmax over n ----
        const int ng = (l >> 4) * 4;
        float m = -1e30f;
        #pragma unroll
        for (int r2 = 0; r2 < 4; ++r2)
            if (ng + r2 < 10) m = fmaxf(m, lg[r2]);
        m = fmaxf(m, __shfl_xor(m, 16));
        m = fmaxf(m, __shfl_xor(m, 32));
        float e[4];
        float ss = 0.f;
        #pragma unroll
        for (int r2 = 0; r2 < 4; ++r2) {
            e[r2] = (ng + r2 < 10) ? __expf(lg[r2] - m) : 0.f;
            ss += e[r2];
        }
        ss += __shfl_xor(ss, 16);
        ss += __shfl_xor(ss, 32);
        const float inv = 1.0f / ss;
        const int posl = w * 16 + (l & 15);
        #pragma unroll
        for (int r2 = 0; r2 < 4; ++r2)
            if (ng + r2 < 10) csm[posl][ng + r2] = e[r2] * inv;
        __syncthreads();

        // ---- p2: wave w owns pos [16w,16w+16); lanes share p (broadcast) ----
        const unsigned* tlu = (const unsigned*)tile;
        #pragma unroll 4
        for (int i = 0; i < 16; ++i) {
            const int p = w * 16 + i;
            const unsigned v = tlu[(p * 16 + ((d2 >> 2) ^ (p & 7))) * 4 + (d2 & 3)];
            const float f0 = bflo(v), f1 = bfhi(v);
            const float4 c03 = *(const float4*)&csm[p][0];  // broadcast
            const float4 c47 = *(const float4*)&csm[p][4];
            const float2 c89 = *(const float2*)&csm[p][8];
            acc[0][0] = fmaf(c03.x, f0, acc[0][0]); acc[0][1] = fmaf(c03.x, f1, acc[0][1]);
            acc[1][0] = fmaf(c03.y, f0, acc[1][0]); acc[1][1] = fmaf(c03.y, f1, acc[1][1]);
            acc[2][0] = fmaf(c03.z, f0, acc[2][0]); acc[2][1] = fmaf(c03.z, f1, acc[2][1]);
            acc[3][0] = fmaf(c03.w, f0, acc[3][0]); acc[3][1] = fmaf(c03.w, f1, acc[3][1]);
            acc[4][0] = fmaf(c47.x, f0, acc[4][0]); acc[4][1] = fmaf(c47.x, f1, acc[4][1]);
            acc[5][0] = fmaf(c47.y, f0, acc[5][0]); acc[5][1] = fmaf(c47.y, f1, acc[5][1]);
            acc[6][0] = fmaf(c47.z, f0, acc[6][0]); acc[6][1] = fmaf(c47.z, f1, acc[6][1]);
            acc[7][0] = fmaf(c47.w, f0, acc[7][0]); acc[7][1] = fmaf(c47.w, f1, acc[7][1]);
            acc[8][0] = fmaf(c89.x, f0, acc[8][0]); acc[8][1] = fmaf(c89.x, f1, acc[8][1]);
            acc[9][0] = fmaf(c89.y, f0, acc[9][0]); acc[9][1] = fmaf(c89.y, f1, acc[9][1]);
        }
    }

    // ---- fold 4 pos-quarter partials (reuse tile region), store pws ----
    __syncthreads();                       // all p2 reads done
    float* red = (float*)smem;             // [4][1280] f32 = 20480 B
    #pragma unroll
    for (int n = 0; n < NCAP; ++n) {
        red[w * 1280 + n * 128 + d2 * 2]     = acc[n][0];
        red[w * 1280 + n * 128 + d2 * 2 + 1] = acc[n][1];
    }
    __syncthreads();
    float* pb = pws + (size_t)(b * 32 + g) * 1280;
    #pragma unroll
    for (int o = 0; o < 5; ++o) {
        const int k = o * 256 + t;
        pb[k] = red[k] + red[1280 + k] + red[2560 + k] + red[3840 + k];
    }
}

extern "C" void kernel_launch(void* const* d_in, const int* in_sizes, int n_in,
                              void* d_out, int out_size, void* d_ws, size_t ws_size,
                              hipStream_t stream) {
    const float* u = (const float*)d_in[0];   // [64][4096][128]
    const float* W = (const float*)d_in[1];   // [128][160]
    float* out = (float*)d_out;               // [64][10][16]
    char* wsb = (char*)d_ws;

    float* partial = (float*)wsb;                       // 1 MB
    float* wbuf    = (float*)(wsb + 1048576);           // 320 KB
    float* pws     = (float*)(wsb + 1376256);           // 10.5 MB

    caps_sum<<<dim3(NB, 32), 256, 0, stream>>>(u, partial);
    caps_small<0><<<NB * NCAP, 128, 0, stream>>>(partial, W, wbuf);   // v1->w1
    route_fx<<<dim3(NB, 32), 256, 0, stream>>>(u, wbuf, pws);         // iter 2
    caps_small<1><<<NB * NCAP, 128, 0, stream>>>(pws, W, wbuf);       // v2->w2
    route_fx<<<dim3(NB, 32), 256, 0, stream>>>(u, wbuf, pws);         // iter 3
    caps_small<2><<<NB * NCAP, 128, 0, stream>>>(pws, W, out);        // v3->out
}